// Round 2
// baseline (81.354 us; speedup 1.0000x reference)
//
#include <hip/hip_runtime.h>

#define SQ 1024
#define DM 1024
#define NH 16
#define HD 64
#define NBH 64   // BATCH*NH

typedef __attribute__((ext_vector_type(8))) _Float16 v8h;
typedef __attribute__((ext_vector_type(4))) float v4f;

__device__ __forceinline__ v4f mfma_f16(v8h a, v8h b, v4f c) {
  return __builtin_amdgcn_mfma_f32_16x16x32_f16(a, b, c, 0, 0, 0);
}

// Build fp16 Q, K' = 0.125*k + rel_k[s], and transposed V'^T where V' = v + rel_v[s].
// Layouts: Qh/Kh: [bh][s][d] (d contiguous, 64), Vth: [bh][d][s] (s contiguous, 1024).
__global__ __launch_bounds__(256) void prep_kernel(
    const float* __restrict__ q, const float* __restrict__ k, const float* __restrict__ v,
    const float* __restrict__ relk, const float* __restrict__ relv,
    _Float16* __restrict__ Qh, _Float16* __restrict__ Kh,
    _Float16* __restrict__ Vth)
{
  __shared__ float vt[64][65];
  int blk = blockIdx.x;            // bh*16 + stile
  int st = blk & 15;
  int bh = blk >> 4;
  int b = bh >> 4, h = bh & 15;
  int s0 = st * 64;
  int t = (int)threadIdx.x;
  int d = t & 63, sl4 = t >> 6;    // 0..3
  const float scale = 0.125f;

  for (int i = 0; i < 16; ++i) {
    int sl = sl4 + i * 4;
    int s = s0 + sl;
    size_t gidx = ((size_t)(b * SQ + s)) * DM + h * HD + d;
    float qv = q[gidx];
    float kv = k[gidx] * scale + relk[s * HD + d];
    float vv = v[gidx] + relv[s * HD + d];
    size_t widx = ((size_t)(bh * SQ + s)) * HD + d;
    Qh[widx] = (_Float16)qv;
    Kh[widx] = (_Float16)kv;
    vt[sl][d] = vv;
  }
  __syncthreads();
  int sl = t & 63, d4 = t >> 6;
  for (int i = 0; i < 16; ++i) {
    int dd = d4 + i * 4;
    Vth[((size_t)(bh * HD + dd)) * SQ + s0 + sl] = (_Float16)vt[sl][dd];
  }
}

// Flash attention fwd. Grid (16 qtiles, 64 bh), 256 threads = 4 waves.
// Wave w owns q rows [q0 + 16w, q0 + 16w + 16). KV tiles of 64.
__global__ __launch_bounds__(256) void attn_kernel(
    const _Float16* __restrict__ Qh, const _Float16* __restrict__ Kh,
    const _Float16* __restrict__ Vth, float* __restrict__ out)
{
  __shared__ _Float16 Kl[64][72];   // [krow][d], pad 8 halves -> 144B rows
  __shared__ _Float16 Vl[64][72];   // [d][kcol]
  __shared__ float Pl[4][16][68];   // per-wave P tile [qrow][kcol], pad 4 f32

  int tid = (int)threadIdx.x;
  int lane = tid & 63, w = tid >> 6;
  int g = lane >> 4, r15 = lane & 15;
  int qt = blockIdx.x;
  int bh = blockIdx.y;
  int b = bh >> 4, h = bh & 15;
  int q0 = qt * 64;
  int qrow = q0 + w * 16 + r15;

  // Q A-fragments: row = lane&15, k(hd) = 8*(lane>>4)+j, for hd-chunks 0-31 / 32-63
  const _Float16* qbase = Qh + ((size_t)(bh * SQ + qrow)) * HD;
  v8h aq0 = *(const v8h*)(qbase + g * 8);
  v8h aq1 = *(const v8h*)(qbase + 32 + g * 8);

  v4f o[4];
  for (int c = 0; c < 4; ++c) o[c] = (v4f){0.f, 0.f, 0.f, 0.f};
  float m_r[4], l_r[4];
  for (int r = 0; r < 4; ++r) { m_r[r] = -1e30f; l_r[r] = 0.f; }

  for (int t0 = 0; t0 < SQ / 64; ++t0) {
    int k0 = t0 * 64;
    // ---- stage K' tile [64][64] and V'^T tile [64][64] ----
    for (int i = 0; i < 2; ++i) {
      int seg = tid + i * 256;             // 512 segments of 8 halves
      int row = seg >> 3, c8 = (seg & 7) * 8;
      *(v8h*)(&Kl[row][c8]) =
          *(const v8h*)(Kh + ((size_t)(bh * SQ + k0 + row)) * HD + c8);
      *(v8h*)(&Vl[row][c8]) =
          *(const v8h*)(Vth + ((size_t)(bh * HD + row)) * SQ + k0 + c8);
    }
    __syncthreads();

    // ---- QK^T: 4 col-chunks of 16 k-rows ----
    v4f sacc[4];
    for (int c = 0; c < 4; ++c) {
      v8h bk0 = *(const v8h*)(&Kl[c * 16 + r15][g * 8]);
      v8h bk1 = *(const v8h*)(&Kl[c * 16 + r15][32 + g * 8]);
      v4f z = (v4f){0.f, 0.f, 0.f, 0.f};
      z = mfma_f16(aq0, bk0, z);
      z = mfma_f16(aq1, bk1, z);
      sacc[c] = z;
    }

    // ---- online softmax (rows = 4g+r, cols = c*16 + r15) ----
    float sc_r[4];
    for (int r = 0; r < 4; ++r) {
      float mx = fmaxf(fmaxf(sacc[0][r], sacc[1][r]), fmaxf(sacc[2][r], sacc[3][r]));
      mx = fmaxf(mx, __shfl_xor(mx, 1));
      mx = fmaxf(mx, __shfl_xor(mx, 2));
      mx = fmaxf(mx, __shfl_xor(mx, 4));
      mx = fmaxf(mx, __shfl_xor(mx, 8));
      float mnew = fmaxf(m_r[r], mx);
      sc_r[r] = __expf(m_r[r] - mnew);
      m_r[r] = mnew;
      float rs = 0.f;
      for (int c = 0; c < 4; ++c) {
        float p = __expf(sacc[c][r] - mnew);
        sacc[c][r] = p;
        rs += p;
      }
      rs += __shfl_xor(rs, 1);
      rs += __shfl_xor(rs, 2);
      rs += __shfl_xor(rs, 4);
      rs += __shfl_xor(rs, 8);
      l_r[r] = l_r[r] * sc_r[r] + rs;
    }
    for (int c = 0; c < 4; ++c)
      for (int r = 0; r < 4; ++r)
        o[c][r] *= sc_r[r];

    // ---- P -> LDS (f32), reshape to A-fragments ----
    for (int c = 0; c < 4; ++c)
      for (int r = 0; r < 4; ++r)
        Pl[w][g * 4 + r][c * 16 + r15] = sacc[c][r];

    v8h pa[2];
    for (int kc = 0; kc < 2; ++kc) {
      const float* pp = &Pl[w][r15][kc * 32 + g * 8];
      v4f p0 = *(const v4f*)(pp);
      v4f p1 = *(const v4f*)(pp + 4);
      v8h ph;
      for (int j = 0; j < 4; ++j) ph[j] = (_Float16)p0[j];
      for (int j = 0; j < 4; ++j) ph[4 + j] = (_Float16)p1[j];
      pa[kc] = ph;
    }

    // ---- PV: out[q][d] += P * V' ----
    for (int c = 0; c < 4; ++c) {
      v8h bv0 = *(const v8h*)(&Vl[c * 16 + r15][g * 8]);
      v8h bv1 = *(const v8h*)(&Vl[c * 16 + r15][32 + g * 8]);
      o[c] = mfma_f16(pa[0], bv0, o[c]);
      o[c] = mfma_f16(pa[1], bv1, o[c]);
    }
    __syncthreads();
  }

  // ---- epilogue: normalize and store fp32 out[b][q][h*64+d] ----
  for (int r = 0; r < 4; ++r) {
    float inv = 1.f / l_r[r];
    int qq = q0 + w * 16 + g * 4 + r;
    for (int c = 0; c < 4; ++c) {
      out[((size_t)(b * SQ + qq)) * DM + h * HD + c * 16 + r15] = o[c][r] * inv;
    }
  }
}

extern "C" void kernel_launch(void* const* d_in, const int* in_sizes, int n_in,
                              void* d_out, int out_size, void* d_ws, size_t ws_size,
                              hipStream_t stream) {
  const float* q = (const float*)d_in[0];
  const float* k = (const float*)d_in[1];
  const float* v = (const float*)d_in[2];
  const float* relk = (const float*)d_in[3];
  const float* relv = (const float*)d_in[4];

  _Float16* Qh = (_Float16*)d_ws;
  _Float16* Kh = Qh + (size_t)NBH * SQ * HD;
  _Float16* Vth = Kh + (size_t)NBH * SQ * HD;

  prep_kernel<<<dim3(NBH * (SQ / 64)), dim3(256), 0, stream>>>(q, k, v, relk, relv, Qh, Kh, Vth);
  attn_kernel<<<dim3(SQ / 64, NBH), dim3(256), 0, stream>>>(Qh, Kh, Vth, (float*)d_out);
}

// Round 4
// 63.033 us; speedup vs baseline: 1.2907x; 1.2907x over previous
//
#include <hip/hip_runtime.h>

#define SQ 1024
#define DM 1024
#define HD 64
#define NBH 64   // BATCH*NH

typedef __attribute__((ext_vector_type(8))) _Float16 v8h;
typedef __attribute__((ext_vector_type(4))) float v4f;
typedef __attribute__((ext_vector_type(2))) __fp16 v2fp16;
typedef __attribute__((ext_vector_type(2))) unsigned int v2u;
typedef __attribute__((ext_vector_type(4))) unsigned int v4u;

__device__ __forceinline__ v4f mfma_f16(v8h a, v8h b, v4f c) {
  return __builtin_amdgcn_mfma_f32_16x16x32_f16(a, b, c, 0, 0, 0);
}

// Build fp16 Q, K' = 0.125*k + rel_k[s], and transposed V'^T where V' = v + rel_v[s].
// Layouts: Qh/Kh: [bh][s][d] (d contiguous, 64), Vth: [bh][d][s] (s contiguous, 1024).
__global__ __launch_bounds__(256) void prep_kernel(
    const float* __restrict__ q, const float* __restrict__ k, const float* __restrict__ v,
    const float* __restrict__ relk, const float* __restrict__ relv,
    _Float16* __restrict__ Qh, _Float16* __restrict__ Kh,
    _Float16* __restrict__ Vth)
{
  __shared__ float vt[64][65];
  int blk = blockIdx.x;            // bh*16 + stile
  int st = blk & 15;
  int bh = blk >> 4;
  int b = bh >> 4, h = bh & 15;
  int s0 = st * 64;
  int t = (int)threadIdx.x;
  int d = t & 63, sl4 = t >> 6;    // 0..3
  const float scale = 0.125f;

  #pragma unroll
  for (int i = 0; i < 16; ++i) {
    int sl = sl4 + i * 4;
    int s = s0 + sl;
    size_t gidx = ((size_t)(b * SQ + s)) * DM + h * HD + d;
    float qv = q[gidx];
    float kv = k[gidx] * scale + relk[s * HD + d];
    float vv = v[gidx] + relv[s * HD + d];
    size_t widx = ((size_t)(bh * SQ + s)) * HD + d;
    Qh[widx] = (_Float16)qv;
    Kh[widx] = (_Float16)kv;
    vt[sl][d] = vv;
  }
  __syncthreads();
  int sl = t & 63, d4 = t >> 6;
  #pragma unroll
  for (int i = 0; i < 16; ++i) {
    int dd = d4 + i * 4;
    Vth[((size_t)(bh * HD + dd)) * SQ + s0 + sl] = (_Float16)vt[sl][dd];
  }
}

// Flash attention fwd, swapped-operand form. Grid (16 qtiles, 64 bh), 4 waves.
// Wave w owns q rows [q0+16w, q0+16w+16). KV tiles of 64.
// QK^T computed as S^T = K'.Q^T  -> lane holds 16 scores of ONE q-row (col=lane&15).
// PV computed as O^T = V'^T.P    -> lane holds 16 outputs of that q-row, d contiguous per reg.
__global__ __launch_bounds__(256) void attn_kernel(
    const _Float16* __restrict__ Qh, const _Float16* __restrict__ Kh,
    const _Float16* __restrict__ Vth, float* __restrict__ out)
{
  __shared__ _Float16 Kl[64][72];   // [krow][d], pad 8 halves -> 144B rows
  __shared__ _Float16 Vl[64][72];   // [d][kcol]
  __shared__ __align__(16) unsigned int Pl[4][16][36];  // per-wave packed-fp16 P, word idx = k>>1

  int tid = (int)threadIdx.x;
  int lane = tid & 63, w = tid >> 6;
  int g = lane >> 4, r15 = lane & 15;
  int qt = blockIdx.x;
  int bh = blockIdx.y;
  int b = bh >> 4, h = bh & 15;
  int q0 = qt * 64;
  int qrow = q0 + w * 16 + r15;

  // Q as B-fragment: col = q = lane&15, k-dim d = 8*(lane>>4)+j
  const _Float16* qbase = Qh + ((size_t)(bh * SQ + qrow)) * HD;
  v8h aq0 = *(const v8h*)(qbase + g * 8);
  v8h aq1 = *(const v8h*)(qbase + 32 + g * 8);

  v4f o[4];
  #pragma unroll
  for (int c = 0; c < 4; ++c) o[c] = (v4f){0.f, 0.f, 0.f, 0.f};
  float m = -3.0e38f, l = 0.f;

  for (int t0 = 0; t0 < SQ / 64; ++t0) {
    int k0 = t0 * 64;
    // ---- stage K' tile [64][64] and V'^T tile [64][64] ----
    #pragma unroll
    for (int i = 0; i < 2; ++i) {
      int seg = tid + i * 256;             // 512 segments of 8 halves
      int row = seg >> 3, c8 = (seg & 7) * 8;
      *(v8h*)(&Kl[row][c8]) =
          *(const v8h*)(Kh + ((size_t)(bh * SQ + k0 + row)) * HD + c8);
      *(v8h*)(&Vl[row][c8]) =
          *(const v8h*)(Vth + ((size_t)(bh * HD + row)) * SQ + k0 + c8);
    }
    __syncthreads();

    // ---- S^T = K'.Q^T : sacc[c][r] = S[q=r15][k = 16c + 4g + r] ----
    v4f sacc[4];
    #pragma unroll
    for (int c = 0; c < 4; ++c) {
      v8h bk0 = *(const v8h*)(&Kl[c * 16 + r15][g * 8]);
      v8h bk1 = *(const v8h*)(&Kl[c * 16 + r15][32 + g * 8]);
      v4f z = (v4f){0.f, 0.f, 0.f, 0.f};
      z = mfma_f16(bk0, aq0, z);
      z = mfma_f16(bk1, aq1, z);
      sacc[c] = z;
    }

    // ---- online softmax: full row reduce = 15 in-lane + 2 shfl ----
    float pm = sacc[0][0];
    #pragma unroll
    for (int c = 0; c < 4; ++c)
      #pragma unroll
      for (int r = 0; r < 4; ++r)
        pm = fmaxf(pm, sacc[c][r]);
    pm = fmaxf(pm, __shfl_xor(pm, 16));
    pm = fmaxf(pm, __shfl_xor(pm, 32));
    float mnew = fmaxf(m, pm);
    float sc = __expf(m - mnew);
    m = mnew;
    float rs = 0.f;
    #pragma unroll
    for (int c = 0; c < 4; ++c)
      #pragma unroll
      for (int r = 0; r < 4; ++r) {
        float p = __expf(sacc[c][r] - mnew);
        sacc[c][r] = p;
        rs += p;
      }
    rs += __shfl_xor(rs, 16);
    rs += __shfl_xor(rs, 32);
    l = l * sc + rs;
    #pragma unroll
    for (int c = 0; c < 4; ++c)
      o[c] *= sc;

    // ---- pack P to fp16 pairs, redistribute via per-wave LDS (vectorized) ----
    // lane holds k = 16c+4g+{0..3}  ->  words widx = 8c+2g+{0,1}
    #pragma unroll
    for (int c = 0; c < 4; ++c) {
      v2fp16 p01 = __builtin_amdgcn_cvt_pkrtz(sacc[c][0], sacc[c][1]);
      v2fp16 p23 = __builtin_amdgcn_cvt_pkrtz(sacc[c][2], sacc[c][3]);
      v2u pack;
      pack[0] = __builtin_bit_cast(unsigned int, p01);
      pack[1] = __builtin_bit_cast(unsigned int, p23);
      *(v2u*)(&Pl[w][r15][8 * c + 2 * g]) = pack;
    }
    __builtin_amdgcn_wave_barrier();   // keep write->read order (same wave, no block sync needed)
    // B-fragment for PV: lane needs P[q=r15][k = 8g+j] and [32+8g+j] -> words 4g.. / 16+4g..
    v8h pb0 = __builtin_bit_cast(v8h, *(const v4u*)(&Pl[w][r15][4 * g]));
    v8h pb1 = __builtin_bit_cast(v8h, *(const v4u*)(&Pl[w][r15][16 + 4 * g]));

    // ---- O^T += V'^T . P : o[c][r] = O[q=r15][d = 16c + 4g + r] ----
    #pragma unroll
    for (int c = 0; c < 4; ++c) {
      v8h bv0 = *(const v8h*)(&Vl[c * 16 + r15][g * 8]);
      v8h bv1 = *(const v8h*)(&Vl[c * 16 + r15][32 + g * 8]);
      o[c] = mfma_f16(bv0, pb0, o[c]);
      o[c] = mfma_f16(bv1, pb1, o[c]);
    }
    __syncthreads();
  }

  // ---- epilogue: normalize, vectorized stores (d contiguous within o[c]) ----
  float inv = 1.f / l;
  #pragma unroll
  for (int c = 0; c < 4; ++c) {
    v4f res = o[c] * inv;
    *(v4f*)(&out[((size_t)(b * SQ + qrow)) * DM + h * HD + 16 * c + 4 * g]) = res;
  }
}

extern "C" void kernel_launch(void* const* d_in, const int* in_sizes, int n_in,
                              void* d_out, int out_size, void* d_ws, size_t ws_size,
                              hipStream_t stream) {
  const float* q = (const float*)d_in[0];
  const float* k = (const float*)d_in[1];
  const float* v = (const float*)d_in[2];
  const float* relk = (const float*)d_in[3];
  const float* relv = (const float*)d_in[4];

  _Float16* Qh = (_Float16*)d_ws;
  _Float16* Kh = Qh + (size_t)NBH * SQ * HD;
  _Float16* Vth = Kh + (size_t)NBH * SQ * HD;

  prep_kernel<<<dim3(NBH * (SQ / 64)), dim3(256), 0, stream>>>(q, k, v, relk, relv, Qh, Kh, Vth);
  attn_kernel<<<dim3(SQ / 64, NBH), dim3(256), 0, stream>>>(Qh, Kh, Vth, (float*)d_out);
}